// Round 7
// baseline (696.002 us; speedup 1.0000x reference)
//
#include <hip/hip_runtime.h>
#include <hip/hip_bf16.h>
#include <math.h>

// Problem constants (AydinConfig: H=1024, I=2048, E=8, K=2; B=4, S=2048)
#define NEXP 8
#define HD 1024
#define ID 2048
#define NTOK 8192          // B*S
#define NROWS 16384        // NTOK * top_k

typedef __bf16 bf16_t;
typedef __bf16 bf16x8 __attribute__((ext_vector_type(8)));
typedef float f32x4 __attribute__((ext_vector_type(4)));

// GEMM tiling (m97 structure, measured-best r1: total 601us, gemm1 202us @683TF)
// MEASURED NOTES (do not regress):
//  - gemm2 variants: BN=128+ybuf+combine (r1, best) > BN=128+atomicAdd (r5,+21us)
//    ~= BN=64+combine (r6, +22us). Keep r1's gemm2.
//  - Occupancy model: CSV VGPR_Count (84) EXCLUDES the 64 acc regs; true total
//    ~148 -> 3 waves/SIMD -> occ 31%. This round: __launch_bounds__(256,4)
//    forces <=128 total -> 4 waves/SIMD (experiment).
//  - LDS conflicts (1.7e7) hidden under TLP; swizzle fix costs VGPRs, net loss (r4).
//  - Deep pipelines (dbuf/counted vmcnt) NULL here (r2/r3).
#define BM 128
#define BK 32
#define MAXT 136           // 128-row tiles: sum ceil(c/128) <= 135

// async global->LDS, 16B per lane. LDS dest must be wave-uniform base + lane*16.
__device__ __forceinline__ void gl16(const void* g, void* l) {
    __builtin_amdgcn_global_load_lds(
        (const __attribute__((address_space(1))) unsigned int*)g,
        (__attribute__((address_space(3))) unsigned int*)l, 16, 0, 0);
}

// ---------------------------------------------------------------- router ----
__global__ __launch_bounds__(256)
void router_kernel(const float* __restrict__ x, const float* __restrict__ rw,
                   bf16_t* __restrict__ xb, int* __restrict__ topk_idx,
                   float* __restrict__ topk_w)
{
    const int t = blockIdx.x;
    const int tid = threadIdx.x;
    const float4 xv = ((const float4*)(x + (size_t)t * HD))[tid];
    float acc[NEXP];
#pragma unroll
    for (int e = 0; e < NEXP; ++e) {
        const float4 w4 = ((const float4*)(rw + e * HD))[tid];
        acc[e] = xv.x * w4.x + xv.y * w4.y + xv.z * w4.z + xv.w * w4.w;
    }
    bf16_t tmp[4] = {(bf16_t)xv.x, (bf16_t)xv.y, (bf16_t)xv.z, (bf16_t)xv.w};
    *(uint2*)(xb + (size_t)t * HD + tid * 4) = *(const uint2*)tmp;

    __shared__ float red[4][NEXP];
    const int lane = tid & 63, wv = tid >> 6;
#pragma unroll
    for (int e = 0; e < NEXP; ++e) {
        float v = acc[e];
#pragma unroll
        for (int off = 32; off >= 1; off >>= 1) v += __shfl_down(v, off, 64);
        if (lane == 0) red[wv][e] = v;
    }
    __syncthreads();
    if (tid == 0) {
        float lg[NEXP], mx = -1e30f;
#pragma unroll
        for (int e = 0; e < NEXP; ++e) {
            lg[e] = red[0][e] + red[1][e] + red[2][e] + red[3][e];
            mx = fmaxf(mx, lg[e]);
        }
        float p[NEXP], s = 0.f;
#pragma unroll
        for (int e = 0; e < NEXP; ++e) { p[e] = __expf(lg[e] - mx); s += p[e]; }
        const float inv = 1.f / s;
#pragma unroll
        for (int e = 0; e < NEXP; ++e) p[e] *= inv;
        int i0 = 0; float p0 = p[0];
#pragma unroll
        for (int e = 1; e < NEXP; ++e) if (p[e] > p0) { p0 = p[e]; i0 = e; }
        int i1 = -1; float p1 = -1.f;
#pragma unroll
        for (int e = 0; e < NEXP; ++e) if (e != i0 && p[e] > p1) { p1 = p[e]; i1 = e; }
        const float d = 1.f / (p0 + p1 + 1e-6f);
        topk_idx[t * 2 + 0] = i0; topk_idx[t * 2 + 1] = i1;
        topk_w[t * 2 + 0] = p0 * d; topk_w[t * 2 + 1] = p1 * d;
    }
}

// ----------------------------------------------------------------- count ----
__global__ __launch_bounds__(256)
void count_kernel(const int* __restrict__ topk_idx, int* __restrict__ counts)
{
    __shared__ int lc[NEXP];
    const int tid = threadIdx.x;
    if (tid < NEXP) lc[tid] = 0;
    __syncthreads();
    const int t = blockIdx.x * 256 + tid;
    atomicAdd(&lc[topk_idx[t * 2 + 0]], 1);
    atomicAdd(&lc[topk_idx[t * 2 + 1]], 1);
    __syncthreads();
    if (tid < NEXP) atomicAdd(&counts[tid], lc[tid]);
}

// ------------------------------------------------------------------ scan ----
__global__ void scan_kernel(const int* __restrict__ counts, int* __restrict__ offsets,
                            int* __restrict__ cursor, unsigned* __restrict__ tile_map)
{
    __shared__ int tb[NEXP + 1];
    if (threadIdx.x == 0) {
        int s = 0, tacc = 0;
        for (int e = 0; e < NEXP; ++e) {
            offsets[e] = s; cursor[e] = s; s += counts[e];
            tb[e] = tacc; tacc += (counts[e] + BM - 1) / BM;
        }
        tb[NEXP] = tacc;
    }
    __syncthreads();
    for (int i = threadIdx.x; i < MAXT; i += 64) {
        unsigned v = 0xFFFFFFFFu;
#pragma unroll
        for (int e = 0; e < NEXP; ++e)
            if (i >= tb[e] && i < tb[e + 1]) v = ((unsigned)e << 16) | (unsigned)(i - tb[e]);
        tile_map[i] = v;
    }
}

// --------------------------------------------------------------- scatter ----
__global__ __launch_bounds__(256)
void scatter_kernel(const int* __restrict__ topk_idx, const float* __restrict__ topk_w,
                    int* __restrict__ cursor, int* __restrict__ token_list,
                    float* __restrict__ row_w, int* __restrict__ row_pos)
{
    __shared__ int lc[NEXP], gbase[NEXP];
    const int tid = threadIdx.x;
    if (tid < NEXP) lc[tid] = 0;
    __syncthreads();
    const int t = blockIdx.x * 256 + tid;
    const int e0 = topk_idx[t * 2 + 0], e1 = topk_idx[t * 2 + 1];
    const int lp0 = atomicAdd(&lc[e0], 1);
    const int lp1 = atomicAdd(&lc[e1], 1);
    __syncthreads();
    if (tid < NEXP) gbase[tid] = atomicAdd(&cursor[tid], lc[tid]);
    __syncthreads();
    const int p0 = gbase[e0] + lp0, p1 = gbase[e1] + lp1;
    token_list[p0] = t; row_w[p0] = topk_w[t * 2 + 0]; row_pos[t * 2 + 0] = p0;
    token_list[p1] = t; row_w[p1] = topk_w[t * 2 + 1]; row_pos[t * 2 + 1] = p1;
}

// -------------------------------------------------------- precast weights ----
__global__ __launch_bounds__(256)
void precast_kernel(const float* __restrict__ src, bf16_t* __restrict__ dst,
                    int K, int N)
{
    const int e = blockIdx.z;
    src += (size_t)e * K * N;
    dst += (size_t)e * K * N;
    const int n0 = blockIdx.x * 64, k0 = blockIdx.y * 64;
    __shared__ float tile[64][65];
    const int tid = threadIdx.x;
    const int tx = (tid & 15) * 4, ty = tid >> 4;
#pragma unroll
    for (int p = 0; p < 4; ++p) {
        const float4 v = *(const float4*)(src + (size_t)(k0 + ty + p * 16) * N + n0 + tx);
        tile[ty + p * 16][tx + 0] = v.x;
        tile[ty + p * 16][tx + 1] = v.y;
        tile[ty + p * 16][tx + 2] = v.z;
        tile[ty + p * 16][tx + 3] = v.w;
    }
    __syncthreads();
    const int n = tid >> 2, kc = (tid & 3) * 16;
    bf16_t outv[16];
#pragma unroll
    for (int j = 0; j < 16; ++j) outv[j] = (bf16_t)tile[kc + j][n];
    bf16_t* d = dst + (size_t)(n0 + n) * K + k0 + kc;
    *(uint4*)d = *(uint4*)outv;
    *(uint4*)(d + 8) = *((uint4*)outv + 1);
}

// ------------------------------------------------- grouped GEMM1 + SwiGLU ----
// r1 core + __launch_bounds__(256,4) (reg cap -> 4 waves/SIMD) + XCD swizzle.
// Grid 32 x 136 = 4352 blocks (divisible by 8).
__global__ __launch_bounds__(256, 4)
void gemm1_kernel(const bf16_t* __restrict__ xb, const bf16_t* __restrict__ w13b,
                  const int* __restrict__ offsets, const int* __restrict__ counts,
                  const int* __restrict__ token_list,
                  const unsigned* __restrict__ tile_map, bf16_t* __restrict__ hbuf)
{
    // bijective XCD chunk transform: xcd k handles a contiguous id range
    unsigned id = blockIdx.y * 32u + blockIdx.x;
    id = (id & 7u) * (4352u >> 3) + (id >> 3);
    const int n0 = (int)(id & 31u) * 64;     // swiglu-col tile (64 gate + 64 up)
    const unsigned tm = tile_map[id >> 5];
    if (tm == 0xFFFFFFFFu) return;
    const int e = (int)(tm >> 16), mt = (int)(tm & 0xFFFFu);
    const int rows = counts[e];
    const int row_base = offsets[e];
    const int r0 = mt * BM;

    __shared__ alignas(16) bf16_t As[128][32];
    __shared__ alignas(16) bf16_t Bg[64][32];
    __shared__ alignas(16) bf16_t Bu[64][32];

    const int tid = threadIdx.x;
    const int lane = tid & 63;
    const int wv = tid >> 6, wr = wv >> 1, wc = wv & 1;
    const int ln15 = lane & 15, q = lane >> 4;

    const int srow = tid >> 2, scol = (tid & 3) * 8;
    int gr0 = row_base + r0 + srow;      if (gr0 > NROWS - 1) gr0 = NROWS - 1;
    int gr1 = row_base + r0 + 64 + srow; if (gr1 > NROWS - 1) gr1 = NROWS - 1;
    const bf16_t* a0 = xb + (size_t)token_list[gr0] * HD + scol;
    const bf16_t* a1 = xb + (size_t)token_list[gr1] * HD + scol;
    const bf16_t* wb = w13b + (size_t)e * HD * (2 * ID);
    const bf16_t* bg = wb + (size_t)(n0 + srow) * HD + scol;        // gate rows
    const bf16_t* bu = wb + (size_t)(ID + n0 + srow) * HD + scol;   // up rows
    bf16_t* const d_a0 = &As[0][0] + tid * 8;
    bf16_t* const d_a1 = &As[64][0] + tid * 8;
    bf16_t* const d_bg = &Bg[0][0] + tid * 8;
    bf16_t* const d_bu = &Bu[0][0] + tid * 8;

    f32x4 accG[4][2], accU[4][2];
#pragma unroll
    for (int i = 0; i < 4; ++i)
#pragma unroll
        for (int j = 0; j < 2; ++j)
#pragma unroll
            for (int c = 0; c < 4; ++c) { accG[i][j][c] = 0.f; accU[i][j][c] = 0.f; }

    for (int k0 = 0; k0 < HD; k0 += BK) {
        gl16(a0, d_a0); gl16(a1, d_a1); gl16(bg, d_bg); gl16(bu, d_bu);
        a0 += BK; a1 += BK; bg += BK; bu += BK;
        __syncthreads();                      // compiler drains vmcnt before barrier

        bf16x8 af[4], bgf[2], buf_[2];
#pragma unroll
        for (int i = 0; i < 4; ++i)
            af[i] = *(const bf16x8*)&As[wr * 64 + i * 16 + ln15][q * 8];
#pragma unroll
        for (int j = 0; j < 2; ++j) {
            bgf[j]  = *(const bf16x8*)&Bg[wc * 32 + j * 16 + ln15][q * 8];
            buf_[j] = *(const bf16x8*)&Bu[wc * 32 + j * 16 + ln15][q * 8];
        }
#pragma unroll
        for (int i = 0; i < 4; ++i)
#pragma unroll
            for (int j = 0; j < 2; ++j) {
                accG[i][j] = __builtin_amdgcn_mfma_f32_16x16x32_bf16(af[i], bgf[j], accG[i][j], 0, 0, 0);
                accU[i][j] = __builtin_amdgcn_mfma_f32_16x16x32_bf16(af[i], buf_[j], accU[i][j], 0, 0, 0);
            }
        __syncthreads();
    }

    // epilogue: SwiGLU in fp32, store bf16. C/D: col=lane&15, row=q*4+reg
#pragma unroll
    for (int i = 0; i < 4; ++i) {
#pragma unroll
        for (int reg = 0; reg < 4; ++reg) {
            const int rr = wr * 64 + i * 16 + q * 4 + reg;
            if (r0 + rr < rows) {
                bf16_t* dst = hbuf + (size_t)(row_base + r0 + rr) * ID + n0 + wc * 32 + ln15;
#pragma unroll
                for (int j = 0; j < 2; ++j) {
                    const float g = accG[i][j][reg], u = accU[i][j][reg];
                    dst[j * 16] = (bf16_t)((g / (1.f + __expf(-g))) * u);
                }
            }
        }
    }
}

// --------------------------------------------------------- grouped GEMM2 ----
// r1 core (BN=128, ybuf plain stores, measured best) + launch_bounds(256,4)
// + XCD swizzle. Grid 8 x 136 = 1088 blocks (divisible by 8).
__global__ __launch_bounds__(256, 4)
void gemm2_kernel(const bf16_t* __restrict__ hbuf, const bf16_t* __restrict__ w2b,
                  const int* __restrict__ offsets, const int* __restrict__ counts,
                  const float* __restrict__ row_w,
                  const unsigned* __restrict__ tile_map, float* __restrict__ ybuf)
{
    unsigned id = blockIdx.y * 8u + blockIdx.x;
    id = (id & 7u) * (1088u >> 3) + (id >> 3);
    const int n0 = (int)(id & 7u) * 128;
    const unsigned tm = tile_map[id >> 3];
    if (tm == 0xFFFFFFFFu) return;
    const int e = (int)(tm >> 16), mt = (int)(tm & 0xFFFFu);
    const int rows = counts[e];
    const int row_base = offsets[e];
    const int r0 = mt * BM;

    __shared__ alignas(16) bf16_t As[128][32];
    __shared__ alignas(16) bf16_t Bs[128][32];
    __shared__ float rww_s[128];

    const int tid = threadIdx.x;
    if (tid < 128) {
        int gr = row_base + r0 + tid; if (gr > NROWS - 1) gr = NROWS - 1;
        rww_s[tid] = row_w[gr];
    }
    const int lane = tid & 63;
    const int wv = tid >> 6, wr = wv >> 1, wc = wv & 1;
    const int ln15 = lane & 15, q = lane >> 4;

    const int srow = tid >> 2, scol = (tid & 3) * 8;
    int gr0 = row_base + r0 + srow;      if (gr0 > NROWS - 1) gr0 = NROWS - 1;
    int gr1 = row_base + r0 + 64 + srow; if (gr1 > NROWS - 1) gr1 = NROWS - 1;
    const bf16_t* a0 = hbuf + (size_t)gr0 * ID + scol;
    const bf16_t* a1 = hbuf + (size_t)gr1 * ID + scol;
    const bf16_t* w2e = w2b + (size_t)e * ID * HD;
    const bf16_t* b0 = w2e + (size_t)(n0 + srow) * ID + scol;
    const bf16_t* b1 = b0 + (size_t)64 * ID;
    bf16_t* const d_a0 = &As[0][0] + tid * 8;
    bf16_t* const d_a1 = &As[64][0] + tid * 8;
    bf16_t* const d_b0 = &Bs[0][0] + tid * 8;
    bf16_t* const d_b1 = &Bs[64][0] + tid * 8;

    f32x4 acc[4][4];
#pragma unroll
    for (int i = 0; i < 4; ++i)
#pragma unroll
        for (int j = 0; j < 4; ++j)
#pragma unroll
            for (int c = 0; c < 4; ++c) acc[i][j][c] = 0.f;

    for (int k0 = 0; k0 < ID; k0 += BK) {
        gl16(a0, d_a0); gl16(a1, d_a1); gl16(b0, d_b0); gl16(b1, d_b1);
        a0 += BK; a1 += BK; b0 += BK; b1 += BK;
        __syncthreads();

        bf16x8 af[4], bf_[4];
#pragma unroll
        for (int i = 0; i < 4; ++i)
            af[i] = *(const bf16x8*)&As[wr * 64 + i * 16 + ln15][q * 8];
#pragma unroll
        for (int j = 0; j < 4; ++j)
            bf_[j] = *(const bf16x8*)&Bs[wc * 64 + j * 16 + ln15][q * 8];
#pragma unroll
        for (int i = 0; i < 4; ++i)
#pragma unroll
            for (int j = 0; j < 4; ++j)
                acc[i][j] = __builtin_amdgcn_mfma_f32_16x16x32_bf16(af[i], bf_[j], acc[i][j], 0, 0, 0);
        __syncthreads();
    }

    // epilogue: weighted plain stores into dense per-row buffer
#pragma unroll
    for (int i = 0; i < 4; ++i) {
#pragma unroll
        for (int reg = 0; reg < 4; ++reg) {
            const int rr = wr * 64 + i * 16 + q * 4 + reg;
            if (r0 + rr < rows) {
                const float w = rww_s[rr];
                float* dst = ybuf + (size_t)(row_base + r0 + rr) * HD + n0 + wc * 64 + ln15;
#pragma unroll
                for (int j = 0; j < 4; ++j)
                    dst[j * 16] = acc[i][j][reg] * w;
            }
        }
    }
}

// --------------------------------------------------------------- combine ----
__global__ __launch_bounds__(256)
void combine_kernel(const float* __restrict__ ybuf, const int* __restrict__ row_pos,
                    float* __restrict__ out)
{
    const int t = blockIdx.x;
    const int p0 = row_pos[t * 2 + 0], p1 = row_pos[t * 2 + 1];
    const float4 a = ((const float4*)(ybuf + (size_t)p0 * HD))[threadIdx.x];
    const float4 b = ((const float4*)(ybuf + (size_t)p1 * HD))[threadIdx.x];
    float4 o; o.x = a.x + b.x; o.y = a.y + b.y; o.z = a.z + b.z; o.w = a.w + b.w;
    ((float4*)(out + (size_t)t * HD))[threadIdx.x] = o;
}

// ---------------------------------------------------------------- launch ----
extern "C" void kernel_launch(void* const* d_in, const int* in_sizes, int n_in,
                              void* d_out, int out_size, void* d_ws, size_t ws_size,
                              hipStream_t stream) {
    const float* x   = (const float*)d_in[0];   // (4,2048,1024)
    const float* rw  = (const float*)d_in[1];   // (8,1024)
    const float* w13 = (const float*)d_in[2];   // (8,1024,4096)
    const float* w2  = (const float*)d_in[3];   // (8,2048,1024)
    float* out = (float*)d_out;                 // (4,2048,1024) fp32

    char* ws = (char*)d_ws;
    int*      counts     = (int*)(ws + 0);
    int*      cursor     = (int*)(ws + 64);
    int*      offsets    = (int*)(ws + 128);
    int*      topk_idx   = (int*)(ws + 256);
    float*    topk_w     = (float*)(ws + 256 + 1 * 65536);
    int*      token_list = (int*)(ws + 256 + 2 * 65536);
    float*    row_w      = (float*)(ws + 256 + 3 * 65536);
    int*      row_pos    = (int*)(ws + 256 + 4 * 65536);
    unsigned* tile_map   = (unsigned*)(ws + 256 + 5 * 65536);
    const size_t MB = 1024 * 1024;
    bf16_t* xb   = (bf16_t*)(ws + 1 * MB);      // 16 MiB
    bf16_t* hbuf = (bf16_t*)(ws + 17 * MB);     // 64 MiB
    bf16_t* w13b = (bf16_t*)(ws + 81 * MB);     // 64 MiB (dead after gemm1)
    float*  ybuf = (float*)(ws + 81 * MB);      // 64 MiB fp32, ALIASES w13b
                                                // (stream-ordered: gemm1 reads,
                                                //  then gemm2 overwrites)
    bf16_t* w2b  = (bf16_t*)(ws + 145 * MB);    // 32 MiB (ends at 177 MiB)

    hipMemsetAsync(ws, 0, 256, stream);         // counts/cursor/offsets

    dim3 gp1(2 * ID / 64, HD / 64, NEXP);       // w13: K=HD, N=2*ID -> [n][k]
    precast_kernel<<<gp1, 256, 0, stream>>>(w13, w13b, HD, 2 * ID);
    dim3 gp2(HD / 64, ID / 64, NEXP);           // w2: K=ID, N=HD -> [n][k]
    precast_kernel<<<gp2, 256, 0, stream>>>(w2, w2b, ID, HD);

    router_kernel<<<NTOK, 256, 0, stream>>>(x, rw, xb, topk_idx, topk_w);
    count_kernel<<<NTOK / 256, 256, 0, stream>>>(topk_idx, counts);
    scan_kernel<<<1, 64, 0, stream>>>(counts, offsets, cursor, tile_map);
    scatter_kernel<<<NTOK / 256, 256, 0, stream>>>(topk_idx, topk_w, cursor,
                                                   token_list, row_w, row_pos);

    dim3 g1(ID / 64, MAXT);                     // 32 x 136 = 4352 blocks
    gemm1_kernel<<<g1, 256, 0, stream>>>(xb, w13b, offsets, counts, token_list,
                                         tile_map, hbuf);
    dim3 g2(HD / 128, MAXT);                    // 8 x 136 = 1088 blocks
    gemm2_kernel<<<g2, 256, 0, stream>>>(hbuf, w2b, offsets, counts, row_w,
                                         tile_map, ybuf);
    combine_kernel<<<NTOK, 256, 0, stream>>>(ybuf, row_pos, out);
}

// Round 8
// 602.203 us; speedup vs baseline: 1.1558x; 1.1558x over previous
//
#include <hip/hip_runtime.h>
#include <hip/hip_bf16.h>
#include <math.h>

// Problem constants (AydinConfig: H=1024, I=2048, E=8, K=2; B=4, S=2048)
#define NEXP 8
#define HD 1024
#define ID 2048
#define NTOK 8192          // B*S
#define NROWS 16384        // NTOK * top_k

typedef __bf16 bf16_t;
typedef __bf16 bf16x8 __attribute__((ext_vector_type(8)));
typedef float f32x4 __attribute__((ext_vector_type(4)));

// MEASURED LEDGER (do not regress):
//  r1 = 601us total; gemm1 202us (occ 31%, MfmaUtil 31%, VGPR_CSV 84 + 64 acc).
//  r5 atomicAdd epilogue +21us; r6 gemm2 BN=64 +22us -> keep BN=128 ybuf+combine.
//  r7 launch_bounds(256,4) on the 4-wave kernel: occ 39% BUT spills
//    (WRITE 65->355MB) -> dur 290us. True need ~148 > 128 cap.
//  => This round: 8-wave/512-thr repartition of the SAME tiles; true need ~100
//     fits the 128-reg granule WITHOUT spills; launch_bounds(512,4) pins it.
//  LDS conflicts (1.7e7) hidden under TLP; r2/r3 pipelining null; r4 swizzle
//  net loss. Keep linear LDS + 2-barrier loop.
#define BM 128
#define BK 32
#define MAXT 136           // 128-row tiles: sum ceil(c/128) <= 135

// async global->LDS, 16B per lane. LDS dest must be wave-uniform base + lane*16.
__device__ __forceinline__ void gl16(const void* g, void* l) {
    __builtin_amdgcn_global_load_lds(
        (const __attribute__((address_space(1))) unsigned int*)g,
        (__attribute__((address_space(3))) unsigned int*)l, 16, 0, 0);
}

// ---------------------------------------------------------------- router ----
__global__ __launch_bounds__(256)
void router_kernel(const float* __restrict__ x, const float* __restrict__ rw,
                   bf16_t* __restrict__ xb, int* __restrict__ topk_idx,
                   float* __restrict__ topk_w)
{
    const int t = blockIdx.x;
    const int tid = threadIdx.x;
    const float4 xv = ((const float4*)(x + (size_t)t * HD))[tid];
    float acc[NEXP];
#pragma unroll
    for (int e = 0; e < NEXP; ++e) {
        const float4 w4 = ((const float4*)(rw + e * HD))[tid];
        acc[e] = xv.x * w4.x + xv.y * w4.y + xv.z * w4.z + xv.w * w4.w;
    }
    bf16_t tmp[4] = {(bf16_t)xv.x, (bf16_t)xv.y, (bf16_t)xv.z, (bf16_t)xv.w};
    *(uint2*)(xb + (size_t)t * HD + tid * 4) = *(const uint2*)tmp;

    __shared__ float red[4][NEXP];
    const int lane = tid & 63, wv = tid >> 6;
#pragma unroll
    for (int e = 0; e < NEXP; ++e) {
        float v = acc[e];
#pragma unroll
        for (int off = 32; off >= 1; off >>= 1) v += __shfl_down(v, off, 64);
        if (lane == 0) red[wv][e] = v;
    }
    __syncthreads();
    if (tid == 0) {
        float lg[NEXP], mx = -1e30f;
#pragma unroll
        for (int e = 0; e < NEXP; ++e) {
            lg[e] = red[0][e] + red[1][e] + red[2][e] + red[3][e];
            mx = fmaxf(mx, lg[e]);
        }
        float p[NEXP], s = 0.f;
#pragma unroll
        for (int e = 0; e < NEXP; ++e) { p[e] = __expf(lg[e] - mx); s += p[e]; }
        const float inv = 1.f / s;
#pragma unroll
        for (int e = 0; e < NEXP; ++e) p[e] *= inv;
        int i0 = 0; float p0 = p[0];
#pragma unroll
        for (int e = 1; e < NEXP; ++e) if (p[e] > p0) { p0 = p[e]; i0 = e; }
        int i1 = -1; float p1 = -1.f;
#pragma unroll
        for (int e = 0; e < NEXP; ++e) if (e != i0 && p[e] > p1) { p1 = p[e]; i1 = e; }
        const float d = 1.f / (p0 + p1 + 1e-6f);
        topk_idx[t * 2 + 0] = i0; topk_idx[t * 2 + 1] = i1;
        topk_w[t * 2 + 0] = p0 * d; topk_w[t * 2 + 1] = p1 * d;
    }
}

// ----------------------------------------------------------------- count ----
__global__ __launch_bounds__(256)
void count_kernel(const int* __restrict__ topk_idx, int* __restrict__ counts)
{
    __shared__ int lc[NEXP];
    const int tid = threadIdx.x;
    if (tid < NEXP) lc[tid] = 0;
    __syncthreads();
    const int t = blockIdx.x * 256 + tid;
    atomicAdd(&lc[topk_idx[t * 2 + 0]], 1);
    atomicAdd(&lc[topk_idx[t * 2 + 1]], 1);
    __syncthreads();
    if (tid < NEXP) atomicAdd(&counts[tid], lc[tid]);
}

// ------------------------------------------------------------------ scan ----
__global__ void scan_kernel(const int* __restrict__ counts, int* __restrict__ offsets,
                            int* __restrict__ cursor, unsigned* __restrict__ tile_map)
{
    __shared__ int tb[NEXP + 1];
    if (threadIdx.x == 0) {
        int s = 0, tacc = 0;
        for (int e = 0; e < NEXP; ++e) {
            offsets[e] = s; cursor[e] = s; s += counts[e];
            tb[e] = tacc; tacc += (counts[e] + BM - 1) / BM;
        }
        tb[NEXP] = tacc;
    }
    __syncthreads();
    for (int i = threadIdx.x; i < MAXT; i += 64) {
        unsigned v = 0xFFFFFFFFu;
#pragma unroll
        for (int e = 0; e < NEXP; ++e)
            if (i >= tb[e] && i < tb[e + 1]) v = ((unsigned)e << 16) | (unsigned)(i - tb[e]);
        tile_map[i] = v;
    }
}

// --------------------------------------------------------------- scatter ----
__global__ __launch_bounds__(256)
void scatter_kernel(const int* __restrict__ topk_idx, const float* __restrict__ topk_w,
                    int* __restrict__ cursor, int* __restrict__ token_list,
                    float* __restrict__ row_w, int* __restrict__ row_pos)
{
    __shared__ int lc[NEXP], gbase[NEXP];
    const int tid = threadIdx.x;
    if (tid < NEXP) lc[tid] = 0;
    __syncthreads();
    const int t = blockIdx.x * 256 + tid;
    const int e0 = topk_idx[t * 2 + 0], e1 = topk_idx[t * 2 + 1];
    const int lp0 = atomicAdd(&lc[e0], 1);
    const int lp1 = atomicAdd(&lc[e1], 1);
    __syncthreads();
    if (tid < NEXP) gbase[tid] = atomicAdd(&cursor[tid], lc[tid]);
    __syncthreads();
    const int p0 = gbase[e0] + lp0, p1 = gbase[e1] + lp1;
    token_list[p0] = t; row_w[p0] = topk_w[t * 2 + 0]; row_pos[t * 2 + 0] = p0;
    token_list[p1] = t; row_w[p1] = topk_w[t * 2 + 1]; row_pos[t * 2 + 1] = p1;
}

// -------------------------------------------------------- precast weights ----
__global__ __launch_bounds__(256)
void precast_kernel(const float* __restrict__ src, bf16_t* __restrict__ dst,
                    int K, int N)
{
    const int e = blockIdx.z;
    src += (size_t)e * K * N;
    dst += (size_t)e * K * N;
    const int n0 = blockIdx.x * 64, k0 = blockIdx.y * 64;
    __shared__ float tile[64][65];
    const int tid = threadIdx.x;
    const int tx = (tid & 15) * 4, ty = tid >> 4;
#pragma unroll
    for (int p = 0; p < 4; ++p) {
        const float4 v = *(const float4*)(src + (size_t)(k0 + ty + p * 16) * N + n0 + tx);
        tile[ty + p * 16][tx + 0] = v.x;
        tile[ty + p * 16][tx + 1] = v.y;
        tile[ty + p * 16][tx + 2] = v.z;
        tile[ty + p * 16][tx + 3] = v.w;
    }
    __syncthreads();
    const int n = tid >> 2, kc = (tid & 3) * 16;
    bf16_t outv[16];
#pragma unroll
    for (int j = 0; j < 16; ++j) outv[j] = (bf16_t)tile[kc + j][n];
    bf16_t* d = dst + (size_t)(n0 + n) * K + k0 + kc;
    *(uint4*)d = *(uint4*)outv;
    *(uint4*)(d + 8) = *((uint4*)outv + 1);
}

// ------------------------------------------------- grouped GEMM1 + SwiGLU ----
// 128-row x 64-swiglu-col tile, 512 thr / 8 waves. Wave = 32 rows x (32 gate
// + 32 up): acc 32 regs, frags 24 -> total ~100 <= 128 granule -> 4 waves/SIMD.
__global__ __launch_bounds__(512, 4)
void gemm1_kernel(const bf16_t* __restrict__ xb, const bf16_t* __restrict__ w13b,
                  const int* __restrict__ offsets, const int* __restrict__ counts,
                  const int* __restrict__ token_list,
                  const unsigned* __restrict__ tile_map, bf16_t* __restrict__ hbuf)
{
    const unsigned tm = tile_map[blockIdx.y];
    if (tm == 0xFFFFFFFFu) return;
    const int e = (int)(tm >> 16), mt = (int)(tm & 0xFFFFu);
    const int rows = counts[e];
    const int row_base = offsets[e];
    const int r0 = mt * BM;
    const int n0 = blockIdx.x * 64;          // swiglu-col tile (64 gate + 64 up)

    __shared__ alignas(16) bf16_t As[128][32];
    __shared__ alignas(16) bf16_t Bg[64][32];
    __shared__ alignas(16) bf16_t Bu[64][32];

    const int tid = threadIdx.x;
    const int lane = tid & 63;
    const int wv = tid >> 6;                 // 0..7
    const int wr = wv >> 1, wc = wv & 1;     // wave: rows [wr*32,+32), cols [wc*32,+32)
    const int ln15 = lane & 15, q = lane >> 4;

    // staging: A by all 512 thr (row tid>>2 of 128); B by half each
    const int srowA = tid >> 2, scol = (tid & 3) * 8;
    const int tb = tid & 255;                // B-staging thread id
    const int srowB = tb >> 2;
    int grA = row_base + r0 + srowA; if (grA > NROWS - 1) grA = NROWS - 1;
    const bf16_t* a0 = xb + (size_t)token_list[grA] * HD + scol;
    const bf16_t* wb = w13b + (size_t)e * HD * (2 * ID);
    // waves 0-3 stage gate rows, waves 4-7 stage up rows (uniform branch)
    const bf16_t* b0 = wb + (size_t)((tid < 256 ? 0 : ID) + n0 + srowB) * HD
                          + (tb & 3) * 8;
    bf16_t* const d_a = &As[0][0] + tid * 8;
    bf16_t* const d_b = (tid < 256 ? &Bg[0][0] : &Bu[0][0]) + tb * 8;

    f32x4 accG[2][2], accU[2][2];
#pragma unroll
    for (int i = 0; i < 2; ++i)
#pragma unroll
        for (int j = 0; j < 2; ++j)
#pragma unroll
            for (int c = 0; c < 4; ++c) { accG[i][j][c] = 0.f; accU[i][j][c] = 0.f; }

    for (int k0 = 0; k0 < HD; k0 += BK) {
        gl16(a0, d_a); gl16(b0, d_b);
        a0 += BK; b0 += BK;
        __syncthreads();

        bf16x8 af[2], bgf[2], buf_[2];
#pragma unroll
        for (int i = 0; i < 2; ++i)
            af[i] = *(const bf16x8*)&As[wr * 32 + i * 16 + ln15][q * 8];
#pragma unroll
        for (int j = 0; j < 2; ++j) {
            bgf[j]  = *(const bf16x8*)&Bg[wc * 32 + j * 16 + ln15][q * 8];
            buf_[j] = *(const bf16x8*)&Bu[wc * 32 + j * 16 + ln15][q * 8];
        }
#pragma unroll
        for (int i = 0; i < 2; ++i)
#pragma unroll
            for (int j = 0; j < 2; ++j) {
                accG[i][j] = __builtin_amdgcn_mfma_f32_16x16x32_bf16(af[i], bgf[j], accG[i][j], 0, 0, 0);
                accU[i][j] = __builtin_amdgcn_mfma_f32_16x16x32_bf16(af[i], buf_[j], accU[i][j], 0, 0, 0);
            }
        __syncthreads();
    }

    // epilogue: SwiGLU in fp32, store bf16. C/D: col=lane&15, row=q*4+reg
#pragma unroll
    for (int i = 0; i < 2; ++i) {
#pragma unroll
        for (int reg = 0; reg < 4; ++reg) {
            const int rr = wr * 32 + i * 16 + q * 4 + reg;
            if (r0 + rr < rows) {
                bf16_t* dst = hbuf + (size_t)(row_base + r0 + rr) * ID + n0 + wc * 32 + ln15;
#pragma unroll
                for (int j = 0; j < 2; ++j) {
                    const float g = accG[i][j][reg], u = accU[i][j][reg];
                    dst[j * 16] = (bf16_t)((g / (1.f + __expf(-g))) * u);
                }
            }
        }
    }
}

// --------------------------------------------------------- grouped GEMM2 ----
// 128x128 tile, 512 thr / 8 waves. Wave = 32 rows x 64 cols: acc 32 regs.
// ybuf plain stores + combine (r1 measured-best epilogue).
__global__ __launch_bounds__(512, 4)
void gemm2_kernel(const bf16_t* __restrict__ hbuf, const bf16_t* __restrict__ w2b,
                  const int* __restrict__ offsets, const int* __restrict__ counts,
                  const float* __restrict__ row_w,
                  const unsigned* __restrict__ tile_map, float* __restrict__ ybuf)
{
    const unsigned tm = tile_map[blockIdx.y];
    if (tm == 0xFFFFFFFFu) return;
    const int e = (int)(tm >> 16), mt = (int)(tm & 0xFFFFu);
    const int rows = counts[e];
    const int row_base = offsets[e];
    const int r0 = mt * BM;
    const int n0 = blockIdx.x * 128;

    __shared__ alignas(16) bf16_t As[128][32];
    __shared__ alignas(16) bf16_t Bs[128][32];
    __shared__ float rww_s[128];

    const int tid = threadIdx.x;
    if (tid < 128) {
        int gr = row_base + r0 + tid; if (gr > NROWS - 1) gr = NROWS - 1;
        rww_s[tid] = row_w[gr];
    }
    const int lane = tid & 63;
    const int wv = tid >> 6;
    const int wr = wv >> 1, wc = wv & 1;     // wave: rows [wr*32,+32), cols [wc*64,+64)
    const int ln15 = lane & 15, q = lane >> 4;

    const int srow = tid >> 2, scol = (tid & 3) * 8;
    int gr0 = row_base + r0 + srow; if (gr0 > NROWS - 1) gr0 = NROWS - 1;
    const bf16_t* a0 = hbuf + (size_t)gr0 * ID + scol;
    const bf16_t* b0 = w2b + (size_t)e * ID * HD + (size_t)(n0 + srow) * ID + scol;
    bf16_t* const d_a = &As[0][0] + tid * 8;
    bf16_t* const d_b = &Bs[0][0] + tid * 8;

    f32x4 acc[2][4];
#pragma unroll
    for (int i = 0; i < 2; ++i)
#pragma unroll
        for (int j = 0; j < 4; ++j)
#pragma unroll
            for (int c = 0; c < 4; ++c) acc[i][j][c] = 0.f;

    for (int k0 = 0; k0 < ID; k0 += BK) {
        gl16(a0, d_a); gl16(b0, d_b);
        a0 += BK; b0 += BK;
        __syncthreads();

        bf16x8 af[2], bf_[4];
#pragma unroll
        for (int i = 0; i < 2; ++i)
            af[i] = *(const bf16x8*)&As[wr * 32 + i * 16 + ln15][q * 8];
#pragma unroll
        for (int j = 0; j < 4; ++j)
            bf_[j] = *(const bf16x8*)&Bs[wc * 64 + j * 16 + ln15][q * 8];
#pragma unroll
        for (int i = 0; i < 2; ++i)
#pragma unroll
            for (int j = 0; j < 4; ++j)
                acc[i][j] = __builtin_amdgcn_mfma_f32_16x16x32_bf16(af[i], bf_[j], acc[i][j], 0, 0, 0);
        __syncthreads();
    }

    // epilogue: weighted plain stores into dense per-row buffer
#pragma unroll
    for (int i = 0; i < 2; ++i) {
#pragma unroll
        for (int reg = 0; reg < 4; ++reg) {
            const int rr = wr * 32 + i * 16 + q * 4 + reg;
            if (r0 + rr < rows) {
                const float w = rww_s[rr];
                float* dst = ybuf + (size_t)(row_base + r0 + rr) * HD + n0 + wc * 64 + ln15;
#pragma unroll
                for (int j = 0; j < 4; ++j)
                    dst[j * 16] = acc[i][j][reg] * w;
            }
        }
    }
}

// --------------------------------------------------------------- combine ----
__global__ __launch_bounds__(256)
void combine_kernel(const float* __restrict__ ybuf, const int* __restrict__ row_pos,
                    float* __restrict__ out)
{
    const int t = blockIdx.x;
    const int p0 = row_pos[t * 2 + 0], p1 = row_pos[t * 2 + 1];
    const float4 a = ((const float4*)(ybuf + (size_t)p0 * HD))[threadIdx.x];
    const float4 b = ((const float4*)(ybuf + (size_t)p1 * HD))[threadIdx.x];
    float4 o; o.x = a.x + b.x; o.y = a.y + b.y; o.z = a.z + b.z; o.w = a.w + b.w;
    ((float4*)(out + (size_t)t * HD))[threadIdx.x] = o;
}

// ---------------------------------------------------------------- launch ----
extern "C" void kernel_launch(void* const* d_in, const int* in_sizes, int n_in,
                              void* d_out, int out_size, void* d_ws, size_t ws_size,
                              hipStream_t stream) {
    const float* x   = (const float*)d_in[0];   // (4,2048,1024)
    const float* rw  = (const float*)d_in[1];   // (8,1024)
    const float* w13 = (const float*)d_in[2];   // (8,1024,4096)
    const float* w2  = (const float*)d_in[3];   // (8,2048,1024)
    float* out = (float*)d_out;                 // (4,2048,1024) fp32

    char* ws = (char*)d_ws;
    int*      counts     = (int*)(ws + 0);
    int*      cursor     = (int*)(ws + 64);
    int*      offsets    = (int*)(ws + 128);
    int*      topk_idx   = (int*)(ws + 256);
    float*    topk_w     = (float*)(ws + 256 + 1 * 65536);
    int*      token_list = (int*)(ws + 256 + 2 * 65536);
    float*    row_w      = (float*)(ws + 256 + 3 * 65536);
    int*      row_pos    = (int*)(ws + 256 + 4 * 65536);
    unsigned* tile_map   = (unsigned*)(ws + 256 + 5 * 65536);
    const size_t MB = 1024 * 1024;
    bf16_t* xb   = (bf16_t*)(ws + 1 * MB);      // 16 MiB
    bf16_t* hbuf = (bf16_t*)(ws + 17 * MB);     // 64 MiB
    bf16_t* w13b = (bf16_t*)(ws + 81 * MB);     // 64 MiB (dead after gemm1)
    float*  ybuf = (float*)(ws + 81 * MB);      // 64 MiB fp32, ALIASES w13b
                                                // (stream-ordered: gemm1 reads,
                                                //  then gemm2 overwrites)
    bf16_t* w2b  = (bf16_t*)(ws + 145 * MB);    // 32 MiB (ends at 177 MiB)

    hipMemsetAsync(ws, 0, 256, stream);         // counts/cursor/offsets

    dim3 gp1(2 * ID / 64, HD / 64, NEXP);       // w13: K=HD, N=2*ID -> [n][k]
    precast_kernel<<<gp1, 256, 0, stream>>>(w13, w13b, HD, 2 * ID);
    dim3 gp2(HD / 64, ID / 64, NEXP);           // w2: K=ID, N=HD -> [n][k]
    precast_kernel<<<gp2, 256, 0, stream>>>(w2, w2b, ID, HD);

    router_kernel<<<NTOK, 256, 0, stream>>>(x, rw, xb, topk_idx, topk_w);
    count_kernel<<<NTOK / 256, 256, 0, stream>>>(topk_idx, counts);
    scan_kernel<<<1, 64, 0, stream>>>(counts, offsets, cursor, tile_map);
    scatter_kernel<<<NTOK / 256, 256, 0, stream>>>(topk_idx, topk_w, cursor,
                                                   token_list, row_w, row_pos);

    dim3 g1(ID / 64, MAXT);                     // 32 x 136 (64 swiglu cols/block)
    gemm1_kernel<<<g1, 512, 0, stream>>>(xb, w13b, offsets, counts, token_list,
                                         tile_map, hbuf);
    dim3 g2(HD / 128, MAXT);                    // 8 x 136
    gemm2_kernel<<<g2, 512, 0, stream>>>(hbuf, w2b, offsets, counts, row_w,
                                         tile_map, ybuf);
    combine_kernel<<<NTOK, 256, 0, stream>>>(ybuf, row_pos, out);
}

// Round 9
// 591.360 us; speedup vs baseline: 1.1770x; 1.0183x over previous
//
#include <hip/hip_runtime.h>
#include <hip/hip_bf16.h>
#include <math.h>

// Problem constants (AydinConfig: H=1024, I=2048, E=8, K=2; B=4, S=2048)
#define NEXP 8
#define HD 1024
#define ID 2048
#define NTOK 8192          // B*S
#define NROWS 16384        // NTOK * top_k

typedef __bf16 bf16_t;
typedef __bf16 bf16x8 __attribute__((ext_vector_type(8)));
typedef float f32x4 __attribute__((ext_vector_type(4)));

// MEASURED LEDGER (do not regress):
//  r1 (4-wave 256thr) = 601us; gemm1 202us, occ 31% (148 true regs -> 3 w/SIMD).
//  r5 atomicAdd epilogue +21us; r6 gemm2 BN=64 +22us -> keep BN=128 ybuf+combine.
//  r7 launch_bounds(256,4): spills (WRITE 65->355MB), 290us. Cap < need = spill.
//  r8 8-wave/512thr repartition: VGPR 36+32acc, occ 60%, dur 199us (~= r1!)
//    -> occupancy NOT the limit; LDS pipe is: 64KB/block-K-step ~= 164us
//       + conflicts 2.6e7 cyc (~42us/CU) now ON the critical path.
//  => r9: involution swizzle (HW-verified 0-conflict in r2/r3/r4) on r8 base.
//     VGPR headroom makes it free now (r4's +4-VGPR penalty was the 6-wave
//     cliff at 84 regs — regime-specific, not general).
#define BM 128
#define BK 32
#define MAXT 136           // 128-row tiles: sum ceil(c/128) <= 135

// async global->LDS, 16B per lane. LDS dest must be wave-uniform base + lane*16.
__device__ __forceinline__ void gl16(const void* g, void* l) {
    __builtin_amdgcn_global_load_lds(
        (const __attribute__((address_space(1))) unsigned int*)g,
        (__attribute__((address_space(3))) unsigned int*)l, 16, 0, 0);
}

// ---------------------------------------------------------------- router ----
__global__ __launch_bounds__(256)
void router_kernel(const float* __restrict__ x, const float* __restrict__ rw,
                   bf16_t* __restrict__ xb, int* __restrict__ topk_idx,
                   float* __restrict__ topk_w)
{
    const int t = blockIdx.x;
    const int tid = threadIdx.x;
    const float4 xv = ((const float4*)(x + (size_t)t * HD))[tid];
    float acc[NEXP];
#pragma unroll
    for (int e = 0; e < NEXP; ++e) {
        const float4 w4 = ((const float4*)(rw + e * HD))[tid];
        acc[e] = xv.x * w4.x + xv.y * w4.y + xv.z * w4.z + xv.w * w4.w;
    }
    bf16_t tmp[4] = {(bf16_t)xv.x, (bf16_t)xv.y, (bf16_t)xv.z, (bf16_t)xv.w};
    *(uint2*)(xb + (size_t)t * HD + tid * 4) = *(const uint2*)tmp;

    __shared__ float red[4][NEXP];
    const int lane = tid & 63, wv = tid >> 6;
#pragma unroll
    for (int e = 0; e < NEXP; ++e) {
        float v = acc[e];
#pragma unroll
        for (int off = 32; off >= 1; off >>= 1) v += __shfl_down(v, off, 64);
        if (lane == 0) red[wv][e] = v;
    }
    __syncthreads();
    if (tid == 0) {
        float lg[NEXP], mx = -1e30f;
#pragma unroll
        for (int e = 0; e < NEXP; ++e) {
            lg[e] = red[0][e] + red[1][e] + red[2][e] + red[3][e];
            mx = fmaxf(mx, lg[e]);
        }
        float p[NEXP], s = 0.f;
#pragma unroll
        for (int e = 0; e < NEXP; ++e) { p[e] = __expf(lg[e] - mx); s += p[e]; }
        const float inv = 1.f / s;
#pragma unroll
        for (int e = 0; e < NEXP; ++e) p[e] *= inv;
        int i0 = 0; float p0 = p[0];
#pragma unroll
        for (int e = 1; e < NEXP; ++e) if (p[e] > p0) { p0 = p[e]; i0 = e; }
        int i1 = -1; float p1 = -1.f;
#pragma unroll
        for (int e = 0; e < NEXP; ++e) if (e != i0 && p[e] > p1) { p1 = p[e]; i1 = e; }
        const float d = 1.f / (p0 + p1 + 1e-6f);
        topk_idx[t * 2 + 0] = i0; topk_idx[t * 2 + 1] = i1;
        topk_w[t * 2 + 0] = p0 * d; topk_w[t * 2 + 1] = p1 * d;
    }
}

// ----------------------------------------------------------------- count ----
__global__ __launch_bounds__(256)
void count_kernel(const int* __restrict__ topk_idx, int* __restrict__ counts)
{
    __shared__ int lc[NEXP];
    const int tid = threadIdx.x;
    if (tid < NEXP) lc[tid] = 0;
    __syncthreads();
    const int t = blockIdx.x * 256 + tid;
    atomicAdd(&lc[topk_idx[t * 2 + 0]], 1);
    atomicAdd(&lc[topk_idx[t * 2 + 1]], 1);
    __syncthreads();
    if (tid < NEXP) atomicAdd(&counts[tid], lc[tid]);
}

// ------------------------------------------------------------------ scan ----
__global__ void scan_kernel(const int* __restrict__ counts, int* __restrict__ offsets,
                            int* __restrict__ cursor, unsigned* __restrict__ tile_map)
{
    __shared__ int tb[NEXP + 1];
    if (threadIdx.x == 0) {
        int s = 0, tacc = 0;
        for (int e = 0; e < NEXP; ++e) {
            offsets[e] = s; cursor[e] = s; s += counts[e];
            tb[e] = tacc; tacc += (counts[e] + BM - 1) / BM;
        }
        tb[NEXP] = tacc;
    }
    __syncthreads();
    for (int i = threadIdx.x; i < MAXT; i += 64) {
        unsigned v = 0xFFFFFFFFu;
#pragma unroll
        for (int e = 0; e < NEXP; ++e)
            if (i >= tb[e] && i < tb[e + 1]) v = ((unsigned)e << 16) | (unsigned)(i - tb[e]);
        tile_map[i] = v;
    }
}

// --------------------------------------------------------------- scatter ----
__global__ __launch_bounds__(256)
void scatter_kernel(const int* __restrict__ topk_idx, const float* __restrict__ topk_w,
                    int* __restrict__ cursor, int* __restrict__ token_list,
                    float* __restrict__ row_w, int* __restrict__ row_pos)
{
    __shared__ int lc[NEXP], gbase[NEXP];
    const int tid = threadIdx.x;
    if (tid < NEXP) lc[tid] = 0;
    __syncthreads();
    const int t = blockIdx.x * 256 + tid;
    const int e0 = topk_idx[t * 2 + 0], e1 = topk_idx[t * 2 + 1];
    const int lp0 = atomicAdd(&lc[e0], 1);
    const int lp1 = atomicAdd(&lc[e1], 1);
    __syncthreads();
    if (tid < NEXP) gbase[tid] = atomicAdd(&cursor[tid], lc[tid]);
    __syncthreads();
    const int p0 = gbase[e0] + lp0, p1 = gbase[e1] + lp1;
    token_list[p0] = t; row_w[p0] = topk_w[t * 2 + 0]; row_pos[t * 2 + 0] = p0;
    token_list[p1] = t; row_w[p1] = topk_w[t * 2 + 1]; row_pos[t * 2 + 1] = p1;
}

// -------------------------------------------------------- precast weights ----
__global__ __launch_bounds__(256)
void precast_kernel(const float* __restrict__ src, bf16_t* __restrict__ dst,
                    int K, int N)
{
    const int e = blockIdx.z;
    src += (size_t)e * K * N;
    dst += (size_t)e * K * N;
    const int n0 = blockIdx.x * 64, k0 = blockIdx.y * 64;
    __shared__ float tile[64][65];
    const int tid = threadIdx.x;
    const int tx = (tid & 15) * 4, ty = tid >> 4;
#pragma unroll
    for (int p = 0; p < 4; ++p) {
        const float4 v = *(const float4*)(src + (size_t)(k0 + ty + p * 16) * N + n0 + tx);
        tile[ty + p * 16][tx + 0] = v.x;
        tile[ty + p * 16][tx + 1] = v.y;
        tile[ty + p * 16][tx + 2] = v.z;
        tile[ty + p * 16][tx + 3] = v.w;
    }
    __syncthreads();
    const int n = tid >> 2, kc = (tid & 3) * 16;
    bf16_t outv[16];
#pragma unroll
    for (int j = 0; j < 16; ++j) outv[j] = (bf16_t)tile[kc + j][n];
    bf16_t* d = dst + (size_t)(n0 + n) * K + k0 + kc;
    *(uint4*)d = *(uint4*)outv;
    *(uint4*)(d + 8) = *((uint4*)outv + 1);
}

// ------------------------------------------------- grouped GEMM1 + SwiGLU ----
// r8 structure (8 waves, 512 thr, wave = 32 rows x (32g+32u), occ 60%) +
// involution swizzle: logical chunk at (row, phys p) = p ^ ((row>>1)&3),
// applied on the gl16 GLOBAL SOURCE and the ds_read chunk; LDS dest linear.
// Row bits 1-2 == ln15 bits 1-2 in all fragment reads (row = 16a + ln15).
__global__ __launch_bounds__(512)
void gemm1_kernel(const bf16_t* __restrict__ xb, const bf16_t* __restrict__ w13b,
                  const int* __restrict__ offsets, const int* __restrict__ counts,
                  const int* __restrict__ token_list,
                  const unsigned* __restrict__ tile_map, bf16_t* __restrict__ hbuf)
{
    const unsigned tm = tile_map[blockIdx.y];
    if (tm == 0xFFFFFFFFu) return;
    const int e = (int)(tm >> 16), mt = (int)(tm & 0xFFFFu);
    const int rows = counts[e];
    const int row_base = offsets[e];
    const int r0 = mt * BM;
    const int n0 = blockIdx.x * 64;          // swiglu-col tile (64 gate + 64 up)

    __shared__ alignas(16) bf16_t As[128][32];
    __shared__ alignas(16) bf16_t Bg[64][32];
    __shared__ alignas(16) bf16_t Bu[64][32];

    const int tid = threadIdx.x;
    const int lane = tid & 63;
    const int wv = tid >> 6;                 // 0..7
    const int wr = wv >> 1, wc = wv & 1;     // wave: rows [wr*32,+32), cols [wc*32,+32)
    const int ln15 = lane & 15, q = lane >> 4;
    const int cs = (q ^ ((ln15 >> 1) & 3)) * 8;   // swizzled read chunk

    // staging: A by all 512 thr (row tid>>2 of 128); B by half each.
    // source chunk swizzled to match read-side XOR (staged row>>1 bits = tid>>3)
    const int srowA = tid >> 2;
    const int scolA = ((tid & 3) ^ ((tid >> 3) & 3)) * 8;
    const int tb = tid & 255;                // B-staging thread id
    const int srowB = tb >> 2;
    const int scolB = ((tb & 3) ^ ((tb >> 3) & 3)) * 8;
    int grA = row_base + r0 + srowA; if (grA > NROWS - 1) grA = NROWS - 1;
    const bf16_t* a0 = xb + (size_t)token_list[grA] * HD + scolA;
    const bf16_t* wb = w13b + (size_t)e * HD * (2 * ID);
    // waves 0-3 stage gate rows, waves 4-7 stage up rows (uniform branch)
    const bf16_t* b0 = wb + (size_t)((tid < 256 ? 0 : ID) + n0 + srowB) * HD + scolB;
    bf16_t* const d_a = &As[0][0] + tid * 8;
    bf16_t* const d_b = (tid < 256 ? &Bg[0][0] : &Bu[0][0]) + tb * 8;

    f32x4 accG[2][2], accU[2][2];
#pragma unroll
    for (int i = 0; i < 2; ++i)
#pragma unroll
        for (int j = 0; j < 2; ++j)
#pragma unroll
            for (int c = 0; c < 4; ++c) { accG[i][j][c] = 0.f; accU[i][j][c] = 0.f; }

    for (int k0 = 0; k0 < HD; k0 += BK) {
        gl16(a0, d_a); gl16(b0, d_b);
        a0 += BK; b0 += BK;
        __syncthreads();

        bf16x8 af[2], bgf[2], buf_[2];
#pragma unroll
        for (int i = 0; i < 2; ++i)
            af[i] = *(const bf16x8*)&As[wr * 32 + i * 16 + ln15][cs];
#pragma unroll
        for (int j = 0; j < 2; ++j) {
            bgf[j]  = *(const bf16x8*)&Bg[wc * 32 + j * 16 + ln15][cs];
            buf_[j] = *(const bf16x8*)&Bu[wc * 32 + j * 16 + ln15][cs];
        }
#pragma unroll
        for (int i = 0; i < 2; ++i)
#pragma unroll
            for (int j = 0; j < 2; ++j) {
                accG[i][j] = __builtin_amdgcn_mfma_f32_16x16x32_bf16(af[i], bgf[j], accG[i][j], 0, 0, 0);
                accU[i][j] = __builtin_amdgcn_mfma_f32_16x16x32_bf16(af[i], buf_[j], accU[i][j], 0, 0, 0);
            }
        __syncthreads();
    }

    // epilogue: SwiGLU in fp32, store bf16. C/D: col=lane&15, row=q*4+reg
#pragma unroll
    for (int i = 0; i < 2; ++i) {
#pragma unroll
        for (int reg = 0; reg < 4; ++reg) {
            const int rr = wr * 32 + i * 16 + q * 4 + reg;
            if (r0 + rr < rows) {
                bf16_t* dst = hbuf + (size_t)(row_base + r0 + rr) * ID + n0 + wc * 32 + ln15;
#pragma unroll
                for (int j = 0; j < 2; ++j) {
                    const float g = accG[i][j][reg], u = accU[i][j][reg];
                    dst[j * 16] = (bf16_t)((g / (1.f + __expf(-g))) * u);
                }
            }
        }
    }
}

// --------------------------------------------------------- grouped GEMM2 ----
// r8 structure (128x128 tile, 8 waves, wave = 32 rows x 64 cols) + swizzle.
// ybuf plain stores + combine (r1 measured-best epilogue).
__global__ __launch_bounds__(512)
void gemm2_kernel(const bf16_t* __restrict__ hbuf, const bf16_t* __restrict__ w2b,
                  const int* __restrict__ offsets, const int* __restrict__ counts,
                  const float* __restrict__ row_w,
                  const unsigned* __restrict__ tile_map, float* __restrict__ ybuf)
{
    const unsigned tm = tile_map[blockIdx.y];
    if (tm == 0xFFFFFFFFu) return;
    const int e = (int)(tm >> 16), mt = (int)(tm & 0xFFFFu);
    const int rows = counts[e];
    const int row_base = offsets[e];
    const int r0 = mt * BM;
    const int n0 = blockIdx.x * 128;

    __shared__ alignas(16) bf16_t As[128][32];
    __shared__ alignas(16) bf16_t Bs[128][32];
    __shared__ float rww_s[128];

    const int tid = threadIdx.x;
    if (tid < 128) {
        int gr = row_base + r0 + tid; if (gr > NROWS - 1) gr = NROWS - 1;
        rww_s[tid] = row_w[gr];
    }
    const int lane = tid & 63;
    const int wv = tid >> 6;
    const int wr = wv >> 1, wc = wv & 1;     // wave: rows [wr*32,+32), cols [wc*64,+64)
    const int ln15 = lane & 15, q = lane >> 4;
    const int cs = (q ^ ((ln15 >> 1) & 3)) * 8;

    const int srow = tid >> 2;
    const int scol = ((tid & 3) ^ ((tid >> 3) & 3)) * 8;
    int gr0 = row_base + r0 + srow; if (gr0 > NROWS - 1) gr0 = NROWS - 1;
    const bf16_t* a0 = hbuf + (size_t)gr0 * ID + scol;
    const bf16_t* b0 = w2b + (size_t)e * ID * HD + (size_t)(n0 + srow) * ID + scol;
    bf16_t* const d_a = &As[0][0] + tid * 8;
    bf16_t* const d_b = &Bs[0][0] + tid * 8;

    f32x4 acc[2][4];
#pragma unroll
    for (int i = 0; i < 2; ++i)
#pragma unroll
        for (int j = 0; j < 4; ++j)
#pragma unroll
            for (int c = 0; c < 4; ++c) acc[i][j][c] = 0.f;

    for (int k0 = 0; k0 < ID; k0 += BK) {
        gl16(a0, d_a); gl16(b0, d_b);
        a0 += BK; b0 += BK;
        __syncthreads();

        bf16x8 af[2], bf_[4];
#pragma unroll
        for (int i = 0; i < 2; ++i)
            af[i] = *(const bf16x8*)&As[wr * 32 + i * 16 + ln15][cs];
#pragma unroll
        for (int j = 0; j < 4; ++j)
            bf_[j] = *(const bf16x8*)&Bs[wc * 64 + j * 16 + ln15][cs];
#pragma unroll
        for (int i = 0; i < 2; ++i)
#pragma unroll
            for (int j = 0; j < 4; ++j)
                acc[i][j] = __builtin_amdgcn_mfma_f32_16x16x32_bf16(af[i], bf_[j], acc[i][j], 0, 0, 0);
        __syncthreads();
    }

    // epilogue: weighted plain stores into dense per-row buffer
#pragma unroll
    for (int i = 0; i < 2; ++i) {
#pragma unroll
        for (int reg = 0; reg < 4; ++reg) {
            const int rr = wr * 32 + i * 16 + q * 4 + reg;
            if (r0 + rr < rows) {
                const float w = rww_s[rr];
                float* dst = ybuf + (size_t)(row_base + r0 + rr) * HD + n0 + wc * 64 + ln15;
#pragma unroll
                for (int j = 0; j < 4; ++j)
                    dst[j * 16] = acc[i][j][reg] * w;
            }
        }
    }
}

// --------------------------------------------------------------- combine ----
__global__ __launch_bounds__(256)
void combine_kernel(const float* __restrict__ ybuf, const int* __restrict__ row_pos,
                    float* __restrict__ out)
{
    const int t = blockIdx.x;
    const int p0 = row_pos[t * 2 + 0], p1 = row_pos[t * 2 + 1];
    const float4 a = ((const float4*)(ybuf + (size_t)p0 * HD))[threadIdx.x];
    const float4 b = ((const float4*)(ybuf + (size_t)p1 * HD))[threadIdx.x];
    float4 o; o.x = a.x + b.x; o.y = a.y + b.y; o.z = a.z + b.z; o.w = a.w + b.w;
    ((float4*)(out + (size_t)t * HD))[threadIdx.x] = o;
}

// ---------------------------------------------------------------- launch ----
extern "C" void kernel_launch(void* const* d_in, const int* in_sizes, int n_in,
                              void* d_out, int out_size, void* d_ws, size_t ws_size,
                              hipStream_t stream) {
    const float* x   = (const float*)d_in[0];   // (4,2048,1024)
    const float* rw  = (const float*)d_in[1];   // (8,1024)
    const float* w13 = (const float*)d_in[2];   // (8,1024,4096)
    const float* w2  = (const float*)d_in[3];   // (8,2048,1024)
    float* out = (float*)d_out;                 // (4,2048,1024) fp32

    char* ws = (char*)d_ws;
    int*      counts     = (int*)(ws + 0);
    int*      cursor     = (int*)(ws + 64);
    int*      offsets    = (int*)(ws + 128);
    int*      topk_idx   = (int*)(ws + 256);
    float*    topk_w     = (float*)(ws + 256 + 1 * 65536);
    int*      token_list = (int*)(ws + 256 + 2 * 65536);
    float*    row_w      = (float*)(ws + 256 + 3 * 65536);
    int*      row_pos    = (int*)(ws + 256 + 4 * 65536);
    unsigned* tile_map   = (unsigned*)(ws + 256 + 5 * 65536);
    const size_t MB = 1024 * 1024;
    bf16_t* xb   = (bf16_t*)(ws + 1 * MB);      // 16 MiB
    bf16_t* hbuf = (bf16_t*)(ws + 17 * MB);     // 64 MiB
    bf16_t* w13b = (bf16_t*)(ws + 81 * MB);     // 64 MiB (dead after gemm1)
    float*  ybuf = (float*)(ws + 81 * MB);      // 64 MiB fp32, ALIASES w13b
                                                // (stream-ordered: gemm1 reads,
                                                //  then gemm2 overwrites)
    bf16_t* w2b  = (bf16_t*)(ws + 145 * MB);    // 32 MiB (ends at 177 MiB)

    hipMemsetAsync(ws, 0, 256, stream);         // counts/cursor/offsets

    dim3 gp1(2 * ID / 64, HD / 64, NEXP);       // w13: K=HD, N=2*ID -> [n][k]
    precast_kernel<<<gp1, 256, 0, stream>>>(w13, w13b, HD, 2 * ID);
    dim3 gp2(HD / 64, ID / 64, NEXP);           // w2: K=ID, N=HD -> [n][k]
    precast_kernel<<<gp2, 256, 0, stream>>>(w2, w2b, ID, HD);

    router_kernel<<<NTOK, 256, 0, stream>>>(x, rw, xb, topk_idx, topk_w);
    count_kernel<<<NTOK / 256, 256, 0, stream>>>(topk_idx, counts);
    scan_kernel<<<1, 64, 0, stream>>>(counts, offsets, cursor, tile_map);
    scatter_kernel<<<NTOK / 256, 256, 0, stream>>>(topk_idx, topk_w, cursor,
                                                   token_list, row_w, row_pos);

    dim3 g1(ID / 64, MAXT);                     // 32 x 136 (64 swiglu cols/block)
    gemm1_kernel<<<g1, 512, 0, stream>>>(xb, w13b, offsets, counts, token_list,
                                         tile_map, hbuf);
    dim3 g2(HD / 128, MAXT);                    // 8 x 136
    gemm2_kernel<<<g2, 512, 0, stream>>>(hbuf, w2b, offsets, counts, row_w,
                                         tile_map, ybuf);
    combine_kernel<<<NTOK, 256, 0, stream>>>(ybuf, row_pos, out);
}